// Round 5
// baseline (579.788 us; speedup 1.0000x reference)
//
#include <hip/hip_runtime.h>

#define NN 50000
#define NE 800000
#define HH 128
#define BN_EPS 1e-5f

typedef unsigned short u16;
typedef unsigned int u32;
typedef short bf16x8 __attribute__((ext_vector_type(8)));
typedef float f32x4 __attribute__((ext_vector_type(4)));

static __device__ __forceinline__ float bf2f(u16 u){
  union { u32 i; float f; } v; v.i = ((u32)u) << 16; return v.f;
}
static __device__ __forceinline__ u16 f2bf(float f){
  union { float f; u32 i; } v; v.f = f;
  u32 x = v.i;
  return (u16)((x + 0x7fffu + ((x >> 16) & 1u)) >> 16);
}
static __device__ __forceinline__ float sigm(float x){
  return 1.f / (1.f + __expf(-x));
}
static __device__ __forceinline__ float tanh_fast(float x){
  return 1.f - 2.f / (1.f + __expf(2.f * x));
}

// ---------------- edge preprocessing ----------------

__global__ void zero_kernel(int* __restrict__ p, int n){
  int i = blockIdx.x * blockDim.x + threadIdx.x;
  if (i < n) p[i] = 0;
}

__global__ void hist_kernel(const int* __restrict__ dst, int* __restrict__ counts, int E){
  int e = blockIdx.x * blockDim.x + threadIdx.x;
  if (e < E) atomicAdd(&counts[dst[e]], 1);
}

__global__ __launch_bounds__(1024) void scan_kernel(
    const int* __restrict__ counts, int* __restrict__ offs,
    int* __restrict__ cursor, int n){
  __shared__ int part[1024];
  int tid = threadIdx.x;
  int chunk = (n + 1023) >> 10;
  int begin = tid * chunk;
  int end   = begin + chunk; if (end > n) end = n;
  int s = 0;
  for (int i = begin; i < end && i >= 0; i++) s += counts[i];
  part[tid] = s;
  __syncthreads();
  for (int off = 1; off < 1024; off <<= 1){
    int v = (tid >= off) ? part[tid - off] : 0;
    __syncthreads();
    part[tid] += v;
    __syncthreads();
  }
  int excl = part[tid] - s;
  for (int i = begin; i < end && i >= 0; i++){
    offs[i] = excl; cursor[i] = excl;
    excl += counts[i];
  }
}

// scatter edges into dst-sorted buckets; pack (src, weight) as int2
__global__ void scatter_kernel(const int* __restrict__ src, const int* __restrict__ dst,
                               const float* __restrict__ w, int* __restrict__ cursor,
                               int2* __restrict__ esw, int E){
  int e = blockIdx.x * blockDim.x + threadIdx.x;
  if (e < E){
    int d = dst[e];
    int pos = atomicAdd(&cursor[d], 1);
    esw[pos] = make_int2(src[e], __float_as_int(w[e]));
  }
}

// ---------------- pack weights to bf16 B^T layouts + bias sums ----------------
// wcat[n=0..511][k=0..255] = [x2h_w | h2h_w] rows; wgcn[n=0..127][k=0..127] = gcn_w^T.
__global__ void prep_pack(const float* __restrict__ x2hw, const float* __restrict__ h2hw,
                          const float* __restrict__ x2hb, const float* __restrict__ h2hb,
                          const float* __restrict__ gcnw,
                          u16* __restrict__ wcat, u16* __restrict__ wgcn,
                          float* __restrict__ bsum){
  int i = blockIdx.x * blockDim.x + threadIdx.x;   // 131072 threads
  int n = i >> 8, k = i & 255;
  float v = (k < 128) ? x2hw[n * 128 + k] : h2hw[n * 128 + (k - 128)];
  wcat[i] = f2bf(v);
  if (i < 16384){
    int nn = i >> 7, kk = i & 127;
    wgcn[i] = f2bf(gcnw[kk * 128 + nn]);   // transpose [k][n] -> [n][k]
  }
  if (i < 512) bsum[i] = x2hb[i] + h2hb[i];
}

// ---------------- support = x @ gcn_weight via MFMA, global-direct ----------------
// block = 64 rows (4 waves x 16); wave covers all 8 n-tiles (128 cols).
// wgcn (32 KB bf16) is L1-resident; no LDS, no barriers.
__global__ __launch_bounds__(256) void support_mfma(
    const float* __restrict__ x, const u16* __restrict__ wgcn,
    u16* __restrict__ support, int N){
  int tid = threadIdx.x;
  int wave = tid >> 6, lane = tid & 63;
  int c = lane & 15, q = lane >> 4;
  int row0 = blockIdx.x * 64 + wave * 16;
  int arow = row0 + c; if (arow > N - 1) arow = N - 1;   // clamp OOB reads
  f32x4 acc[8];
#pragma unroll
  for (int t = 0; t < 8; t++) acc[t] = (f32x4){0.f, 0.f, 0.f, 0.f};

  const u16* wp = wgcn + (size_t)c * 128 + q * 8;
#pragma unroll
  for (int k0 = 0; k0 < 128; k0 += 32){
    const float* ap = x + (size_t)arow * 128 + k0 + q * 8;
    float4 f0 = *(const float4*)ap;
    float4 f1 = *(const float4*)(ap + 4);
    u16 tmp[8] = {f2bf(f0.x), f2bf(f0.y), f2bf(f0.z), f2bf(f0.w),
                  f2bf(f1.x), f2bf(f1.y), f2bf(f1.z), f2bf(f1.w)};
    bf16x8 afrag = *(bf16x8*)tmp;
#pragma unroll
    for (int t = 0; t < 8; t++){
      bf16x8 bfrag = *(const bf16x8*)(wp + (size_t)t * 16 * 128 + k0);
      acc[t] = __builtin_amdgcn_mfma_f32_16x16x32_bf16(afrag, bfrag, acc[t], 0, 0, 0);
    }
  }
#pragma unroll
  for (int t = 0; t < 8; t++){
#pragma unroll
    for (int j = 0; j < 4; j++){
      int r = row0 + q * 4 + j;
      if (r < N) support[(size_t)r * 128 + t * 16 + c] = f2bf(acc[t][j]);
    }
  }
}

// ---------------- CSR aggregate + relu + bias + BN -> h_bn (bf16) ----------------
// one wave per node; lane covers 2 columns; edge (src,w) staged via shuffle broadcast
__global__ __launch_bounds__(256) void agg_bn(
    const u16* __restrict__ support, const int2* __restrict__ esw,
    const int* __restrict__ offs, const int* __restrict__ counts,
    const float* __restrict__ bias, const float* __restrict__ gamma,
    const float* __restrict__ beta, const float* __restrict__ mean,
    const float* __restrict__ var,
    u16* __restrict__ hbn, int N){
  int wid = blockIdx.x * 4 + (threadIdx.x >> 6);
  int lane = threadIdx.x & 63;
  if (wid >= N) return;
  int start = offs[wid];
  int deg   = counts[wid];
  int c = lane * 2;
  float a0 = 0.f, a1 = 0.f;
  for (int base = 0; base < deg; base += 64){
    int cnt = deg - base; if (cnt > 64) cnt = 64;
    int2 my = make_int2(0, 0);
    if (lane < cnt) my = esw[start + base + lane];
    for (int e = 0; e < cnt; e++){
      int   s = __shfl(my.x, e);
      float g = __int_as_float(__shfl(my.y, e));
      u32 u = *(const u32*)(support + (size_t)s * HH + c);
      a0 = fmaf(g, bf2f((u16)(u & 0xffffu)), a0);
      a1 = fmaf(g, bf2f((u16)(u >> 16)), a1);
    }
  }
  float h0 = fmaxf(a0, 0.f) + bias[c];
  float h1 = fmaxf(a1, 0.f) + bias[c + 1];
  float s0 = gamma[c]     * rsqrtf(var[c]     + BN_EPS);
  float s1 = gamma[c + 1] * rsqrtf(var[c + 1] + BN_EPS);
  float r0 = (h0 - mean[c])     * s0 + beta[c];
  float r1 = (h1 - mean[c + 1]) * s1 + beta[c + 1];
  u32 pack = (u32)f2bf(r0) | ((u32)f2bf(r1) << 16);
  *(u32*)(hbn + (size_t)wid * HH + c) = pack;
}

// ---------------- gates GEMM via MFMA, global-direct, barrier-free ----------------
// block = 64 rows (4 waves x 16); wave covers all 32 n-tiles (512 cols) so the
// LSTM epilogue is register-local (i/f/g/o at tiles tb, tb+8, tb+16, tb+24).
// A = [hbn bf16 | hx fp32->bf16]; B^T = wcat[512][256] bf16 (256 KB, L2-hot).
// No LDS, no __syncthreads.
__global__ __launch_bounds__(256) void gates_mfma(
    const u16* __restrict__ hbn, const float* __restrict__ hx,
    const u16* __restrict__ wcat, const float* __restrict__ bsum,
    const float* __restrict__ cx, float* __restrict__ out, int N){
  int tid = threadIdx.x;
  int wave = tid >> 6, lane = tid & 63;
  int c = lane & 15, q = lane >> 4;
  int row0 = blockIdx.x * 64 + wave * 16;
  int arow = row0 + c; if (arow > N - 1) arow = N - 1;   // clamp OOB reads
  f32x4 acc[32];
#pragma unroll
  for (int t = 0; t < 32; t++) acc[t] = (f32x4){0.f, 0.f, 0.f, 0.f};

  const u16* wp = wcat + (size_t)c * 256 + q * 8;
  // k half 1: A = hbn (bf16, direct)
#pragma unroll
  for (int k0 = 0; k0 < 128; k0 += 32){
    bf16x8 afrag = *(const bf16x8*)(hbn + (size_t)arow * 128 + k0 + q * 8);
#pragma unroll
    for (int t = 0; t < 32; t++){
      bf16x8 bfrag = *(const bf16x8*)(wp + (size_t)t * 16 * 256 + k0);
      acc[t] = __builtin_amdgcn_mfma_f32_16x16x32_bf16(afrag, bfrag, acc[t], 0, 0, 0);
    }
  }
  // k half 2: A = hx (fp32 -> bf16 in registers)
#pragma unroll
  for (int k0 = 128; k0 < 256; k0 += 32){
    const float* ap = hx + (size_t)arow * 128 + (k0 - 128) + q * 8;
    float4 f0 = *(const float4*)ap;
    float4 f1 = *(const float4*)(ap + 4);
    u16 tmp[8] = {f2bf(f0.x), f2bf(f0.y), f2bf(f0.z), f2bf(f0.w),
                  f2bf(f1.x), f2bf(f1.y), f2bf(f1.z), f2bf(f1.w)};
    bf16x8 afrag = *(bf16x8*)tmp;
#pragma unroll
    for (int t = 0; t < 32; t++){
      bf16x8 bfrag = *(const bf16x8*)(wp + (size_t)t * 16 * 256 + k0);
      acc[t] = __builtin_amdgcn_mfma_f32_16x16x32_bf16(afrag, bfrag, acc[t], 0, 0, 0);
    }
  }

  // fused LSTM epilogue (register-local gates)
  const size_t NH = (size_t)N * HH;
#pragma unroll
  for (int tb = 0; tb < 8; tb++){
    int h = tb * 16 + c;
    float bi = bsum[h];
    float bf_ = bsum[128 + h];
    float bg = bsum[256 + h];
    float bo = bsum[384 + h];
#pragma unroll
    for (int j = 0; j < 4; j++){
      int r = row0 + q * 4 + j;
      if (r < N){
        float gi = acc[tb][j]      + bi;
        float gf = acc[tb + 8][j]  + bf_;
        float gg = acc[tb + 16][j] + bg;
        float go = acc[tb + 24][j] + bo;
        float is = sigm(gi), fs = sigm(gf), gt = tanh_fast(gg), os = sigm(go);
        float co = cx[(size_t)r * HH + h];
        float cyv = co * fs + is * gt;
        out[(size_t)r * HH + h]      = os * tanh_fast(cyv);
        out[NH + (size_t)r * HH + h] = cyv;
      }
    }
  }
}

// ---------------- launch ----------------

extern "C" void kernel_launch(void* const* d_in, const int* in_sizes, int n_in,
                              void* d_out, int out_size, void* d_ws, size_t ws_size,
                              hipStream_t stream){
  const float* x     = (const float*)d_in[0];
  const float* hx    = (const float*)d_in[1];
  const float* cx    = (const float*)d_in[2];
  const int*   esrc  = (const int*)d_in[3];
  const int*   edst  = (const int*)d_in[4];
  const float* ew    = (const float*)d_in[5];
  const float* gcn_w = (const float*)d_in[6];
  const float* bias  = (const float*)d_in[7];
  const float* x2hw  = (const float*)d_in[8];
  const float* x2hb  = (const float*)d_in[9];
  const float* h2hw  = (const float*)d_in[10];
  const float* h2hb  = (const float*)d_in[11];
  const float* bn_g  = (const float*)d_in[12];
  const float* bn_b  = (const float*)d_in[13];
  const float* bn_m  = (const float*)d_in[14];
  const float* bn_v  = (const float*)d_in[15];
  float* out = (float*)d_out;

  char* w = (char*)d_ws;
  u16* support = (u16*)w; w += (((size_t)NN * HH * 2) + 255) & ~(size_t)255;
  u16* hbn     = (u16*)w; w += (((size_t)NN * HH * 2) + 255) & ~(size_t)255;
  int* counts  = (int*)w; w += (((size_t)NN * 4) + 255) & ~(size_t)255;
  int* offs    = (int*)w; w += (((size_t)NN * 4) + 255) & ~(size_t)255;
  int* cursor  = (int*)w; w += (((size_t)NN * 4) + 255) & ~(size_t)255;
  int2* esw    = (int2*)w; w += (((size_t)NE * 8) + 255) & ~(size_t)255;
  u16* wcat    = (u16*)w; w += (((size_t)512 * 256 * 2) + 255) & ~(size_t)255;
  u16* wgcn    = (u16*)w; w += (((size_t)128 * 128 * 2) + 255) & ~(size_t)255;
  float* bsum  = (float*)w; w += (((size_t)512 * 4) + 255) & ~(size_t)255;

  prep_pack<<<512, 256, 0, stream>>>(x2hw, h2hw, x2hb, h2hb, gcn_w, wcat, wgcn, bsum);
  zero_kernel<<<(NN + 255) / 256, 256, 0, stream>>>(counts, NN);
  hist_kernel<<<(NE + 255) / 256, 256, 0, stream>>>(edst, counts, NE);
  scan_kernel<<<1, 1024, 0, stream>>>(counts, offs, cursor, NN);
  scatter_kernel<<<(NE + 255) / 256, 256, 0, stream>>>(esrc, edst, ew, cursor, esw, NE);
  support_mfma<<<(NN + 63) / 64, 256, 0, stream>>>(x, wgcn, support, NN);
  agg_bn<<<(NN + 3) / 4, 256, 0, stream>>>(support, esw, offs, counts,
                                           bias, bn_g, bn_b, bn_m, bn_v, hbn, NN);
  gates_mfma<<<(NN + 63) / 64, 256, 0, stream>>>(hbn, hx, wcat, bsum, cx, out, NN);
}

// Round 6
// 508.593 us; speedup vs baseline: 1.1400x; 1.1400x over previous
//
#include <hip/hip_runtime.h>

#define NN 50000
#define NE 800000
#define HH 128
#define BN_EPS 1e-5f

typedef unsigned short u16;
typedef unsigned int u32;
typedef short bf16x8 __attribute__((ext_vector_type(8)));
typedef float f32x4 __attribute__((ext_vector_type(4)));

static __device__ __forceinline__ float bf2f(u16 u){
  union { u32 i; float f; } v; v.i = ((u32)u) << 16; return v.f;
}
static __device__ __forceinline__ u16 f2bf(float f){
  union { float f; u32 i; } v; v.f = f;
  u32 x = v.i;
  return (u16)((x + 0x7fffu + ((x >> 16) & 1u)) >> 16);
}
static __device__ __forceinline__ float sigm(float x){
  return 1.f / (1.f + __expf(-x));
}
static __device__ __forceinline__ float tanh_fast(float x){
  return 1.f - 2.f / (1.f + __expf(2.f * x));
}

// ---------------- edge preprocessing ----------------

__global__ void zero_kernel(int* __restrict__ p, int n){
  int i = blockIdx.x * blockDim.x + threadIdx.x;
  if (i < n) p[i] = 0;
}

__global__ void hist_kernel(const int* __restrict__ dst, int* __restrict__ counts, int E){
  int e = blockIdx.x * blockDim.x + threadIdx.x;
  if (e < E) atomicAdd(&counts[dst[e]], 1);
}

__global__ __launch_bounds__(1024) void scan_kernel(
    const int* __restrict__ counts, int* __restrict__ offs,
    int* __restrict__ cursor, int n){
  __shared__ int part[1024];
  int tid = threadIdx.x;
  int chunk = (n + 1023) >> 10;
  int begin = tid * chunk;
  int end   = begin + chunk; if (end > n) end = n;
  int s = 0;
  for (int i = begin; i < end && i >= 0; i++) s += counts[i];
  part[tid] = s;
  __syncthreads();
  for (int off = 1; off < 1024; off <<= 1){
    int v = (tid >= off) ? part[tid - off] : 0;
    __syncthreads();
    part[tid] += v;
    __syncthreads();
  }
  int excl = part[tid] - s;
  for (int i = begin; i < end && i >= 0; i++){
    offs[i] = excl; cursor[i] = excl;
    excl += counts[i];
  }
}

// scatter edges into dst-sorted buckets; pack (src, weight) as int2
__global__ void scatter_kernel(const int* __restrict__ src, const int* __restrict__ dst,
                               const float* __restrict__ w, int* __restrict__ cursor,
                               int2* __restrict__ esw, int E){
  int e = blockIdx.x * blockDim.x + threadIdx.x;
  if (e < E){
    int d = dst[e];
    int pos = atomicAdd(&cursor[d], 1);
    esw[pos] = make_int2(src[e], __float_as_int(w[e]));
  }
}

// ---------------- pack weights to bf16 B^T layouts + bias sums ----------------

__global__ void prep_pack(const float* __restrict__ x2hw, const float* __restrict__ h2hw,
                          const float* __restrict__ x2hb, const float* __restrict__ h2hb,
                          const float* __restrict__ gcnw,
                          u16* __restrict__ wcat, u16* __restrict__ wgcn,
                          float* __restrict__ bsum){
  int i = blockIdx.x * blockDim.x + threadIdx.x;   // 131072 threads
  int n = i >> 8, k = i & 255;
  float v = (k < 128) ? x2hw[n * 128 + k] : h2hw[n * 128 + (k - 128)];
  wcat[i] = f2bf(v);
  if (i < 16384){
    int nn = i >> 7, kk = i & 127;
    wgcn[i] = f2bf(gcnw[kk * 128 + nn]);   // transpose [k][n] -> [n][k]
  }
  if (i < 512) bsum[i] = x2hb[i] + h2hb[i];
}

// ---------------- support = x @ gcn_weight via MFMA, global-direct ----------------
// block = 64 rows (4 waves x 16); wave covers all 8 n-tiles (128 cols).
// wgcn (32 KB bf16) is L1-resident; no LDS, no barriers.
__global__ __launch_bounds__(256) void support_mfma(
    const float* __restrict__ x, const u16* __restrict__ wgcn,
    u16* __restrict__ support, int N){
  int tid = threadIdx.x;
  int wave = tid >> 6, lane = tid & 63;
  int c = lane & 15, q = lane >> 4;
  int row0 = blockIdx.x * 64 + wave * 16;
  int arow = row0 + c; if (arow > N - 1) arow = N - 1;   // clamp OOB reads
  f32x4 acc[8];
#pragma unroll
  for (int t = 0; t < 8; t++) acc[t] = (f32x4){0.f, 0.f, 0.f, 0.f};

  const u16* wp = wgcn + (size_t)c * 128 + q * 8;
#pragma unroll
  for (int k0 = 0; k0 < 128; k0 += 32){
    const float* ap = x + (size_t)arow * 128 + k0 + q * 8;
    float4 f0 = *(const float4*)ap;
    float4 f1 = *(const float4*)(ap + 4);
    u16 tmp[8] = {f2bf(f0.x), f2bf(f0.y), f2bf(f0.z), f2bf(f0.w),
                  f2bf(f1.x), f2bf(f1.y), f2bf(f1.z), f2bf(f1.w)};
    bf16x8 afrag = *(bf16x8*)tmp;
#pragma unroll
    for (int t = 0; t < 8; t++){
      bf16x8 bfrag = *(const bf16x8*)(wp + (size_t)t * 16 * 128 + k0);
      acc[t] = __builtin_amdgcn_mfma_f32_16x16x32_bf16(afrag, bfrag, acc[t], 0, 0, 0);
    }
  }
#pragma unroll
  for (int t = 0; t < 8; t++){
#pragma unroll
    for (int j = 0; j < 4; j++){
      int r = row0 + q * 4 + j;
      if (r < N) support[(size_t)r * 128 + t * 16 + c] = f2bf(acc[t][j]);
    }
  }
}

// ---------------- CSR aggregate + relu + bias + BN -> h_bn (bf16) ----------------

__global__ __launch_bounds__(256) void agg_bn(
    const u16* __restrict__ support, const int2* __restrict__ esw,
    const int* __restrict__ offs, const int* __restrict__ counts,
    const float* __restrict__ bias, const float* __restrict__ gamma,
    const float* __restrict__ beta, const float* __restrict__ mean,
    const float* __restrict__ var,
    u16* __restrict__ hbn, int N){
  int wid = blockIdx.x * 4 + (threadIdx.x >> 6);
  int lane = threadIdx.x & 63;
  if (wid >= N) return;
  int start = offs[wid];
  int deg   = counts[wid];
  int c = lane * 2;
  float a0 = 0.f, a1 = 0.f;
  for (int base = 0; base < deg; base += 64){
    int cnt = deg - base; if (cnt > 64) cnt = 64;
    int2 my = make_int2(0, 0);
    if (lane < cnt) my = esw[start + base + lane];
    for (int e = 0; e < cnt; e++){
      int   s = __shfl(my.x, e);
      float g = __int_as_float(__shfl(my.y, e));
      u32 u = *(const u32*)(support + (size_t)s * HH + c);
      a0 = fmaf(g, bf2f((u16)(u & 0xffffu)), a0);
      a1 = fmaf(g, bf2f((u16)(u >> 16)), a1);
    }
  }
  float h0 = fmaxf(a0, 0.f) + bias[c];
  float h1 = fmaxf(a1, 0.f) + bias[c + 1];
  float s0 = gamma[c]     * rsqrtf(var[c]     + BN_EPS);
  float s1 = gamma[c + 1] * rsqrtf(var[c + 1] + BN_EPS);
  float r0 = (h0 - mean[c])     * s0 + beta[c];
  float r1 = (h1 - mean[c + 1]) * s1 + beta[c + 1];
  u32 pack = (u32)f2bf(r0) | ((u32)f2bf(r1) << 16);
  *(u32*)(hbn + (size_t)wid * HH + c) = pack;
}

// ---------------- gates GEMM via MFMA, gate-split tiling, barrier-free ----------------
// block = 32 rows (2 bands x 16), 4 waves. Wave w owns n-tiles {g*8 + 2w + p}
// for gate g in 0..3, p in 0..1  ->  h in [32w, 32w+32) for ALL FOUR gates:
// epilogue stays register-local with only 8 tiles (acc = 64 VGPR, not 128).
// Each B-frag is reused across 2 row-bands. No LDS, no barriers.
__global__ __launch_bounds__(256, 4) void gates_mfma(
    const u16* __restrict__ hbn, const float* __restrict__ hx,
    const u16* __restrict__ wcat, const float* __restrict__ bsum,
    const float* __restrict__ cx, float* __restrict__ out, int N){
  int tid = threadIdx.x;
  int wave = tid >> 6, lane = tid & 63;
  int c = lane & 15, q = lane >> 4;
  int row0 = blockIdx.x * 32;
  int ar0 = row0 + c;      if (ar0 > N - 1) ar0 = N - 1;
  int ar1 = row0 + 16 + c; if (ar1 > N - 1) ar1 = N - 1;
  f32x4 acc[2][8];
#pragma unroll
  for (int b = 0; b < 2; b++)
#pragma unroll
    for (int t = 0; t < 8; t++) acc[b][t] = (f32x4){0.f, 0.f, 0.f, 0.f};

  // per-tile B row pointers: tile t -> gate g=t>>1, pair p=t&1
  const u16* wp[8];
#pragma unroll
  for (int t = 0; t < 8; t++){
    int ntile = (t >> 1) * 8 + wave * 2 + (t & 1);
    wp[t] = wcat + (size_t)(ntile * 16 + c) * 256 + q * 8;
  }

  // k half 1: A = hbn (bf16, direct)
#pragma unroll
  for (int k0 = 0; k0 < 128; k0 += 32){
    bf16x8 a0 = *(const bf16x8*)(hbn + (size_t)ar0 * 128 + k0 + q * 8);
    bf16x8 a1 = *(const bf16x8*)(hbn + (size_t)ar1 * 128 + k0 + q * 8);
#pragma unroll
    for (int t = 0; t < 8; t++){
      bf16x8 bfrag = *(const bf16x8*)(wp[t] + k0);
      acc[0][t] = __builtin_amdgcn_mfma_f32_16x16x32_bf16(a0, bfrag, acc[0][t], 0, 0, 0);
      acc[1][t] = __builtin_amdgcn_mfma_f32_16x16x32_bf16(a1, bfrag, acc[1][t], 0, 0, 0);
    }
  }
  // k half 2: A = hx (fp32 -> bf16 in registers)
#pragma unroll
  for (int k0 = 128; k0 < 256; k0 += 32){
    const float* p0 = hx + (size_t)ar0 * 128 + (k0 - 128) + q * 8;
    const float* p1 = hx + (size_t)ar1 * 128 + (k0 - 128) + q * 8;
    float4 f00 = *(const float4*)p0;
    float4 f01 = *(const float4*)(p0 + 4);
    float4 f10 = *(const float4*)p1;
    float4 f11 = *(const float4*)(p1 + 4);
    u16 t0[8] = {f2bf(f00.x), f2bf(f00.y), f2bf(f00.z), f2bf(f00.w),
                 f2bf(f01.x), f2bf(f01.y), f2bf(f01.z), f2bf(f01.w)};
    u16 t1[8] = {f2bf(f10.x), f2bf(f10.y), f2bf(f10.z), f2bf(f10.w),
                 f2bf(f11.x), f2bf(f11.y), f2bf(f11.z), f2bf(f11.w)};
    bf16x8 a0 = *(bf16x8*)t0;
    bf16x8 a1 = *(bf16x8*)t1;
#pragma unroll
    for (int t = 0; t < 8; t++){
      bf16x8 bfrag = *(const bf16x8*)(wp[t] + k0);
      acc[0][t] = __builtin_amdgcn_mfma_f32_16x16x32_bf16(a0, bfrag, acc[0][t], 0, 0, 0);
      acc[1][t] = __builtin_amdgcn_mfma_f32_16x16x32_bf16(a1, bfrag, acc[1][t], 0, 0, 0);
    }
  }

  // fused LSTM epilogue (register-local: i/f/g/o at tiles p, 2+p, 4+p, 6+p)
  const size_t NH = (size_t)N * HH;
#pragma unroll
  for (int b = 0; b < 2; b++){
#pragma unroll
    for (int p = 0; p < 2; p++){
      int h = (wave * 2 + p) * 16 + c;
      float bi  = bsum[h];
      float bf_ = bsum[128 + h];
      float bg  = bsum[256 + h];
      float bo  = bsum[384 + h];
#pragma unroll
      for (int j = 0; j < 4; j++){
        int r = row0 + b * 16 + q * 4 + j;
        if (r < N){
          float gi = acc[b][0 + p][j] + bi;
          float gf = acc[b][2 + p][j] + bf_;
          float gg = acc[b][4 + p][j] + bg;
          float go = acc[b][6 + p][j] + bo;
          float is = sigm(gi), fs = sigm(gf), gt = tanh_fast(gg), os = sigm(go);
          float co = cx[(size_t)r * HH + h];
          float cyv = co * fs + is * gt;
          out[(size_t)r * HH + h]      = os * tanh_fast(cyv);
          out[NH + (size_t)r * HH + h] = cyv;
        }
      }
    }
  }
}

// ---------------- launch ----------------

extern "C" void kernel_launch(void* const* d_in, const int* in_sizes, int n_in,
                              void* d_out, int out_size, void* d_ws, size_t ws_size,
                              hipStream_t stream){
  const float* x     = (const float*)d_in[0];
  const float* hx    = (const float*)d_in[1];
  const float* cx    = (const float*)d_in[2];
  const int*   esrc  = (const int*)d_in[3];
  const int*   edst  = (const int*)d_in[4];
  const float* ew    = (const float*)d_in[5];
  const float* gcn_w = (const float*)d_in[6];
  const float* bias  = (const float*)d_in[7];
  const float* x2hw  = (const float*)d_in[8];
  const float* x2hb  = (const float*)d_in[9];
  const float* h2hw  = (const float*)d_in[10];
  const float* h2hb  = (const float*)d_in[11];
  const float* bn_g  = (const float*)d_in[12];
  const float* bn_b  = (const float*)d_in[13];
  const float* bn_m  = (const float*)d_in[14];
  const float* bn_v  = (const float*)d_in[15];
  float* out = (float*)d_out;

  char* w = (char*)d_ws;
  u16* support = (u16*)w; w += (((size_t)NN * HH * 2) + 255) & ~(size_t)255;
  u16* hbn     = (u16*)w; w += (((size_t)NN * HH * 2) + 255) & ~(size_t)255;
  int* counts  = (int*)w; w += (((size_t)NN * 4) + 255) & ~(size_t)255;
  int* offs    = (int*)w; w += (((size_t)NN * 4) + 255) & ~(size_t)255;
  int* cursor  = (int*)w; w += (((size_t)NN * 4) + 255) & ~(size_t)255;
  int2* esw    = (int2*)w; w += (((size_t)NE * 8) + 255) & ~(size_t)255;
  u16* wcat    = (u16*)w; w += (((size_t)512 * 256 * 2) + 255) & ~(size_t)255;
  u16* wgcn    = (u16*)w; w += (((size_t)128 * 128 * 2) + 255) & ~(size_t)255;
  float* bsum  = (float*)w; w += (((size_t)512 * 4) + 255) & ~(size_t)255;

  prep_pack<<<512, 256, 0, stream>>>(x2hw, h2hw, x2hb, h2hb, gcn_w, wcat, wgcn, bsum);
  zero_kernel<<<(NN + 255) / 256, 256, 0, stream>>>(counts, NN);
  hist_kernel<<<(NE + 255) / 256, 256, 0, stream>>>(edst, counts, NE);
  scan_kernel<<<1, 1024, 0, stream>>>(counts, offs, cursor, NN);
  scatter_kernel<<<(NE + 255) / 256, 256, 0, stream>>>(esrc, edst, ew, cursor, esw, NE);
  support_mfma<<<(NN + 63) / 64, 256, 0, stream>>>(x, wgcn, support, NN);
  agg_bn<<<(NN + 3) / 4, 256, 0, stream>>>(support, esw, offs, counts,
                                           bias, bn_g, bn_b, bn_m, bn_v, hbn, NN);
  gates_mfma<<<(NN + 31) / 32, 256, 0, stream>>>(hbn, hx, wcat, bsum, cx, out, NN);
}